// Round 5
// baseline (3464.326 us; speedup 1.0000x reference)
//
#include <hip/hip_runtime.h>

#define T_SEQ 2048
#define HDIM  128
#define GDIM  512
#define BATCH 256

typedef _Float16 f16;
typedef _Float16 f16x2 __attribute__((ext_vector_type(2)));
typedef _Float16 f16x8 __attribute__((ext_vector_type(8)));

#if __has_builtin(__builtin_amdgcn_fdot2)
__device__ __forceinline__ float dot2(f16x2 a, f16x2 b, float c) {
    return __builtin_amdgcn_fdot2(a, b, c, false);
}
#else
__device__ __forceinline__ float dot2(f16x2 a, f16x2 b, float c) {
    return c + (float)a[0] * (float)b[0] + (float)a[1] * (float)b[1];
}
#endif

__device__ __forceinline__ f16x2 mk2(float a, float b) {
    f16x2 r; r[0] = (f16)a; r[1] = (f16)b; return r;
}
__device__ __forceinline__ f16x2 pr(f16x8 v, int m) {
    f16x2 r; r[0] = v[2 * m]; r[1] = v[2 * m + 1]; return r;
}
__device__ __forceinline__ float sigm(float x) {
    return __builtin_amdgcn_rcpf(1.0f + __expf(-x));
}
__device__ __forceinline__ float tanh_fast(float x) {
    float e = __expf(2.0f * x);
    return 1.0f - 2.0f * __builtin_amdgcn_rcpf(e + 1.0f);
}

// ======================= chunked two-kernel path =======================
//
// Rounds 2-4 proved 1024-thread workgroups are pinned at a 64-VGPR budget
// on this toolchain (waves_per_eu attributes change SGPR count but not
// VGPR), so the 96-weight-VGPR fused design always spills (155 MB scratch
// writes). Rounds 0-1 proved 512-thread workgroups DO get 128 VGPRs.
// Layers couple only through h0(t) and each block owns one batch element,
// so split by layer in time: K1 scans layer0 over a chunk and materializes
// (a) xg1p[t] = bias1 + Wih1[:,0:64] . h0[0:64](t)   (f32, exact)
// (b) h0hi[t] = h0[64:128](t)                        (f16)
// K2 scans layer1 over the same chunk, streaming (a)+(b).
// Per-thread register weights: K1 = Whh0 row (64) + Wih1 low (32) = 96;
// K2 = Whh1 row (64) + Wih1 high (32) = 96. ~116 total demand <= 128.

__global__ __launch_bounds__(512, 2)
void lstm_l0(const float* __restrict__ x,
             const float* __restrict__ Wih0,
             const float* __restrict__ Whh0,
             const float* __restrict__ bih0,
             const float* __restrict__ bhh0,
             const float* __restrict__ Wih1,
             const float* __restrict__ bih1,
             const float* __restrict__ bhh1,
             float* __restrict__ h0s,  float* __restrict__ c0s,
             float* __restrict__ xg1p, f16* __restrict__ h0hi,
             int t0, int len, int first, int last,
             float* __restrict__ out)
{
    __shared__ __align__(16) float xsc[T_SEQ];   // x chunk (<= 8 KB)
    __shared__ __align__(16) f16   h0h[HDIM];    // h0 state, f16 dot input
    __shared__ float h0f[HDIM];                  // f32 copy for outputs/state
    __shared__ float g0[GDIM];                   // layer0 gate preactivations

    const int t = threadIdx.x;
    const int b = blockIdx.x;

    for (int idx = t; idx < len; idx += 512)
        xsc[idx] = x[(size_t)b * T_SEQ + t0 + idx];

    // ---- per-thread weights: 96 VGPRs ----
    f16x2 wa[64];  // W_hh_l0[t, 0:128]
    f16x2 wb[32];  // W_ih_l1[t, 0:64]
    {
        const float4* pa = (const float4*)(Whh0 + t * HDIM);
        const float4* pb = (const float4*)(Wih1 + t * HDIM);
#pragma unroll
        for (int c = 0; c < 32; ++c) {
            float4 v = pa[c];
            wa[2 * c]     = mk2(v.x, v.y);
            wa[2 * c + 1] = mk2(v.z, v.w);
        }
#pragma unroll
        for (int c = 0; c < 16; ++c) {
            float4 v = pb[c];
            wb[2 * c]     = mk2(v.x, v.y);
            wb[2 * c + 1] = mk2(v.z, v.w);
        }
    }
    const float wx0   = Wih0[t];
    const float bias0 = bih0[t] + bhh0[t];
    const float b1    = bih1[t] + bhh1[t];

    float c0r = 0.f;
    if (t < HDIM) {
        float h = first ? 0.f : h0s[b * HDIM + t];
        if (!first) c0r = c0s[b * HDIM + t];
        h0f[t] = h;
        h0h[t] = (f16)h;
    }
    __syncthreads();

    const f16x8* h0p = (const f16x8*)h0h;
    float* xgB = xg1p + (size_t)b * len * 512;
    f16*   hhB = h0hi + (size_t)b * len * 64;

    // software pipeline: iter i computes layer0 step i (uses h0(i-1)) AND
    // the layer1 input partial for step i-1 (also h0(i-1)).
    for (int i = 0; i <= len; ++i) {
        float s0a = (i < len ? xsc[i] : 0.f) * wx0 + bias0;
        float s0b = 0.f, s0c = 0.f, s0d = 0.f;
        float s1a = b1, s1b = 0.f;
#pragma unroll
        for (int c = 0; c < 16; ++c) {
            f16x8 h = h0p[c];
            s0a = dot2(wa[4 * c + 0], pr(h, 0), s0a);
            s0b = dot2(wa[4 * c + 1], pr(h, 1), s0b);
            s0c = dot2(wa[4 * c + 2], pr(h, 2), s0c);
            s0d = dot2(wa[4 * c + 3], pr(h, 3), s0d);
            if (c < 8) {  // k = 0..63 for the layer1 input partial
                s1a = dot2(wb[4 * c + 0], pr(h, 0), s1a);
                s1b = dot2(wb[4 * c + 1], pr(h, 1), s1b);
                s1a = dot2(wb[4 * c + 2], pr(h, 2), s1a);
                s1b = dot2(wb[4 * c + 3], pr(h, 3), s1b);
            }
        }
        if (i < len) g0[t] = (s0a + s0b) + (s0c + s0d);
        if (i >= 1)  xgB[(size_t)(i - 1) * 512 + t] = s1a + s1b;
        __syncthreads();

        if (t < 128 && i < len) {
            float gi = sigm(g0[t]);
            float gf = sigm(g0[t + 128]);
            float gg = tanh_fast(g0[t + 256]);
            float go = sigm(g0[t + 384]);
            c0r = gf * c0r + gi * gg;
            float h = go * tanh_fast(c0r);
            h0h[t] = (f16)h;
            h0f[t] = h;
            if (t >= 64) hhB[(size_t)i * 64 + (t - 64)] = (f16)h;
        }
        __syncthreads();
    }

    if (t < 128) {
        h0s[b * HDIM + t] = h0f[t];
        c0s[b * HDIM + t] = c0r;
        if (last) {
            float* hn = out + BATCH;
            float* cn = out + BATCH + 2 * BATCH * HDIM;
            hn[(size_t)b * HDIM + t] = h0f[t];
            cn[(size_t)b * HDIM + t] = c0r;
        }
    }
}

__global__ __launch_bounds__(512, 2)
void lstm_l1(const float* __restrict__ Whh1,
             const float* __restrict__ Wih1,
             const float* __restrict__ Wfc,
             const float* __restrict__ bfc,
             float* __restrict__ h1s, float* __restrict__ c1s,
             const float* __restrict__ xg1p, const f16* __restrict__ h0hi,
             int len, int first, int last,
             float* __restrict__ out)
{
    __shared__ __align__(16) f16   h1h[HDIM];
    __shared__ float h1f[HDIM];
    __shared__ float g1[GDIM];
    __shared__ __align__(16) f16   hh[2][64];   // h0hi double buffer

    const int t = threadIdx.x;
    const int b = blockIdx.x;

    // ---- per-thread weights: 96 VGPRs ----
    f16x2 wa[64];  // W_hh_l1[t, 0:128]
    f16x2 wb[32];  // W_ih_l1[t, 64:128]
    {
        const float4* pa = (const float4*)(Whh1 + t * HDIM);
        const float4* pb = (const float4*)(Wih1 + t * HDIM + 64);
#pragma unroll
        for (int c = 0; c < 32; ++c) {
            float4 v = pa[c];
            wa[2 * c]     = mk2(v.x, v.y);
            wa[2 * c + 1] = mk2(v.z, v.w);
        }
#pragma unroll
        for (int c = 0; c < 16; ++c) {
            float4 v = pb[c];
            wb[2 * c]     = mk2(v.x, v.y);
            wb[2 * c + 1] = mk2(v.z, v.w);
        }
    }

    float c1r = 0.f;
    if (t < HDIM) {
        float h = first ? 0.f : h1s[b * HDIM + t];
        if (!first) c1r = c1s[b * HDIM + t];
        h1f[t] = h;
        h1h[t] = (f16)h;
    }

    const float* xgB = xg1p + (size_t)b * len * 512;
    const f16*   hB  = h0hi + (size_t)b * len * 64;
    if (t < 8) ((f16x8*)hh[0])[t] = ((const f16x8*)hB)[t];   // stage step 0
    float xgv = xgB[t];
    __syncthreads();

    const f16x8* h1p = (const f16x8*)h1h;

    for (int i = 0; i < len; ++i) {
        // prefetch step i+1 (latency hidden under this step's compute)
        float xgn = 0.f;
        if (i + 1 < len) {
            xgn = xgB[(size_t)(i + 1) * 512 + t];
            if (t < 8)
                ((f16x8*)hh[(i + 1) & 1])[t] =
                    ((const f16x8*)(hB + (size_t)(i + 1) * 64))[t];
        }
        const f16x8* hhp = (const f16x8*)hh[i & 1];

        float s1a = xgv, s1b = 0.f, s1c = 0.f, s1d = 0.f;
#pragma unroll
        for (int c = 0; c < 16; ++c) {
            f16x8 h = h1p[c];
            s1a = dot2(wa[4 * c + 0], pr(h, 0), s1a);
            s1b = dot2(wa[4 * c + 1], pr(h, 1), s1b);
            s1c = dot2(wa[4 * c + 2], pr(h, 2), s1c);
            s1d = dot2(wa[4 * c + 3], pr(h, 3), s1d);
            if (c < 8) {  // Wih1 high half x h0hi
                f16x8 hx = hhp[c];
                s1c = dot2(wb[4 * c + 0], pr(hx, 0), s1c);
                s1d = dot2(wb[4 * c + 1], pr(hx, 1), s1d);
                s1c = dot2(wb[4 * c + 2], pr(hx, 2), s1c);
                s1d = dot2(wb[4 * c + 3], pr(hx, 3), s1d);
            }
        }
        g1[t] = (s1a + s1b) + (s1c + s1d);
        __syncthreads();

        if (t < 128) {
            float gi = sigm(g1[t]);
            float gf = sigm(g1[t + 128]);
            float gg = tanh_fast(g1[t + 256]);
            float go = sigm(g1[t + 384]);
            c1r = gf * c1r + gi * gg;
            float h = go * tanh_fast(c1r);
            h1h[t] = (f16)h;
            h1f[t] = h;
        }
        __syncthreads();
        xgv = xgn;
    }

    if (t < 128) {
        h1s[b * HDIM + t] = h1f[t];
        c1s[b * HDIM + t] = c1r;
        if (last) {
            float* hn = out + BATCH;
            float* cn = out + BATCH + 2 * BATCH * HDIM;
            hn[BATCH * HDIM + (size_t)b * HDIM + t] = h1f[t];
            cn[BATCH * HDIM + (size_t)b * HDIM + t] = c1r;
        }
    }
    if (last && t < 64) {
        float p = h1f[t] * Wfc[t] + h1f[t + 64] * Wfc[t + 64];
#pragma unroll
        for (int o = 32; o >= 1; o >>= 1) p += __shfl_down(p, o);
        if (t == 0) out[b] = p + bfc[0];
    }
}

// ======================= fallback (small workspace) =======================
__global__ __launch_bounds__(1024)
void lstm_fused(const float* __restrict__ x,
                const float* __restrict__ Wih0,
                const float* __restrict__ Whh0,
                const float* __restrict__ bih0,
                const float* __restrict__ bhh0,
                const float* __restrict__ Wih1,
                const float* __restrict__ Whh1,
                const float* __restrict__ bih1,
                const float* __restrict__ bhh1,
                const float* __restrict__ Wfc,
                const float* __restrict__ bfc,
                float* __restrict__ out)
{
    __shared__ __align__(16) float xs[T_SEQ];
    __shared__ __align__(16) f16   h0h[HDIM];
    __shared__ __align__(16) f16   h1h[HDIM];
    __shared__ float h0f[HDIM], h1f[HDIM];
    __shared__ float g0[GDIM];
    __shared__ float g1a[GDIM], g1b[GDIM];

    const int t  = threadIdx.x;
    const int b  = blockIdx.x;
    const bool gA = (t < 512);
    const int r  = t & 511;

    if (gA)
        ((float4*)xs)[t] = ((const float4*)(x + (size_t)b * T_SEQ))[t];

    f16x2 wa[64];
    f16x2 wb[32];
    {
        const float4* pa = (const float4*)((gA ? Whh0 : Wih1) + r * HDIM);
        const float4* pb = (const float4*)(Whh1 + r * HDIM + (gA ? 0 : 64));
#pragma unroll
        for (int c = 0; c < 32; ++c) {
            float4 v = pa[c];
            wa[2 * c]     = mk2(v.x, v.y);
            wa[2 * c + 1] = mk2(v.z, v.w);
        }
#pragma unroll
        for (int c = 0; c < 16; ++c) {
            float4 v = pb[c];
            wb[2 * c]     = mk2(v.x, v.y);
            wb[2 * c + 1] = mk2(v.z, v.w);
        }
    }
    const float xw   = gA ? Wih0[r] : 0.f;
    const float bias = gA ? (bih0[r] + bhh0[r]) : (bih1[r] + bhh1[r]);

    if (t < HDIM) {
        h0h[t] = (f16)0.f; h1h[t] = (f16)0.f;
        h0f[t] = 0.f;      h1f[t] = 0.f;
    }
    float c0r = 0.f, c1r = 0.f;
    __syncthreads();

    const f16x8* h0p  = (const f16x8*)h0h;
    const f16x8* hsel = ((const f16x8*)h1h) + (gA ? 0 : 8);

    for (int i = 0; i <= T_SEQ; ++i) {
        float sa = (i < T_SEQ ? xs[i] : 0.f) * xw + bias;
        float sb = 0.f, sc = 0.f, sd = 0.f;
#pragma unroll
        for (int c = 0; c < 16; ++c) {
            f16x8 h = h0p[c];
            sa = dot2(wa[4 * c + 0], pr(h, 0), sa);
            sb = dot2(wa[4 * c + 1], pr(h, 1), sb);
            sa = dot2(wa[4 * c + 2], pr(h, 2), sa);
            sb = dot2(wa[4 * c + 3], pr(h, 3), sb);
        }
#pragma unroll
        for (int c = 0; c < 8; ++c) {
            f16x8 h = hsel[c];
            sc = dot2(wb[4 * c + 0], pr(h, 0), sc);
            sd = dot2(wb[4 * c + 1], pr(h, 1), sd);
            sc = dot2(wb[4 * c + 2], pr(h, 2), sc);
            sd = dot2(wb[4 * c + 3], pr(h, 3), sd);
        }
        if (gA) { g0[r] = sa + sb; g1a[r] = sc + sd; }
        else    { g1b[r] = (sa + sb) + (sc + sd); }
        __syncthreads();

        if (t < 128) {
            if (i < T_SEQ) {
                float gi = sigm(g0[t]);
                float gf = sigm(g0[t + 128]);
                float gg = tanh_fast(g0[t + 256]);
                float go = sigm(g0[t + 384]);
                c0r = gf * c0r + gi * gg;
                float h = go * tanh_fast(c0r);
                h0h[t] = (f16)h;
                h0f[t] = h;
            }
        } else if (t >= 512 && t < 640) {
            if (i >= 1) {
                int j = t - 512;
                float gi = sigm(g1a[j]       + g1b[j]);
                float gf = sigm(g1a[j + 128] + g1b[j + 128]);
                float gg = tanh_fast(g1a[j + 256] + g1b[j + 256]);
                float go = sigm(g1a[j + 384] + g1b[j + 384]);
                c1r = gf * c1r + gi * gg;
                float h = go * tanh_fast(c1r);
                h1h[j] = (f16)h;
                h1f[j] = h;
            }
        }
        __syncthreads();
    }

    float* hn = out + BATCH;
    float* cn = out + BATCH + 2 * BATCH * HDIM;
    if (t < 128) {
        hn[(size_t)b * HDIM + t] = h0f[t];
        cn[(size_t)b * HDIM + t] = c0r;
    } else if (t >= 512 && t < 640) {
        int j = t - 512;
        hn[BATCH * HDIM + (size_t)b * HDIM + j] = h1f[j];
        cn[BATCH * HDIM + (size_t)b * HDIM + j] = c1r;
    }
    if (t < 64) {
        float p = h1f[t] * Wfc[t] + h1f[t + 64] * Wfc[t + 64];
#pragma unroll
        for (int o = 32; o >= 1; o >>= 1) p += __shfl_down(p, o);
        if (t == 0) out[b] = p + bfc[0];
    }
}

extern "C" void kernel_launch(void* const* d_in, const int* in_sizes, int n_in,
                              void* d_out, int out_size, void* d_ws, size_t ws_size,
                              hipStream_t stream) {
    const float* x    = (const float*)d_in[0];
    const float* Wih0 = (const float*)d_in[1];
    const float* Whh0 = (const float*)d_in[2];
    const float* bih0 = (const float*)d_in[3];
    const float* bhh0 = (const float*)d_in[4];
    const float* Wih1 = (const float*)d_in[5];
    const float* Whh1 = (const float*)d_in[6];
    const float* bih1 = (const float*)d_in[7];
    const float* bhh1 = (const float*)d_in[8];
    const float* Wfc  = (const float*)d_in[9];
    const float* bfc  = (const float*)d_in[10];
    float* out = (float*)d_out;

    // workspace layout: [h0s|c0s|h1s|c1s][xg1p: B*CH*512 f32][h0hi: B*CH*64 f16]
    const size_t stateB  = (size_t)4 * BATCH * HDIM * sizeof(float);   // 512 KB
    const size_t perStep = (size_t)BATCH * 512 * 4 + (size_t)BATCH * 64 * 2;
    long long ch = 0;
    if (d_ws && ws_size > stateB) ch = (long long)((ws_size - stateB) / perStep);
    if (ch > T_SEQ) ch = T_SEQ;

    if (ch >= 64) {
        const int CH = (int)ch;
        float* h0s  = (float*)d_ws;
        float* c0s  = h0s + BATCH * HDIM;
        float* h1s  = c0s + BATCH * HDIM;
        float* c1s  = h1s + BATCH * HDIM;
        float* xg1p = c1s + BATCH * HDIM;
        f16*   h0hi = (f16*)(xg1p + (size_t)BATCH * CH * 512);
        for (int t0 = 0; t0 < T_SEQ; t0 += CH) {
            const int len   = (T_SEQ - t0 < CH) ? (T_SEQ - t0) : CH;
            const int first = (t0 == 0);
            const int last  = (t0 + len == T_SEQ);
            lstm_l0<<<BATCH, 512, 0, stream>>>(x, Wih0, Whh0, bih0, bhh0,
                                               Wih1, bih1, bhh1,
                                               h0s, c0s, xg1p, h0hi,
                                               t0, len, first, last, out);
            lstm_l1<<<BATCH, 512, 0, stream>>>(Whh1, Wih1, Wfc, bfc,
                                               h1s, c1s, xg1p, h0hi,
                                               len, first, last, out);
        }
    } else {
        lstm_fused<<<BATCH, 1024, 0, stream>>>(x, Wih0, Whh0, bih0, bhh0,
                                               Wih1, Whh1, bih1, bhh1,
                                               Wfc, bfc, out);
    }
}

// Round 6
// 2964.052 us; speedup vs baseline: 1.1688x; 1.1688x over previous
//
#include <hip/hip_runtime.h>

#define T_SEQ 2048
#define HDIM  128
#define GDIM  512
#define BATCH 256
#define GW_PLANES 8                          // Whh1[:,64:128] streamed via L2
#define WS_NEED (GW_PLANES * GDIM * 16)      // 64 KB f16-packed in workspace

typedef _Float16 f16;
typedef _Float16 f16x2 __attribute__((ext_vector_type(2)));
typedef _Float16 f16x8 __attribute__((ext_vector_type(8)));

#if __has_builtin(__builtin_amdgcn_fdot2)
__device__ __forceinline__ float dot2(f16x2 a, f16x2 b, float c) {
    return __builtin_amdgcn_fdot2(a, b, c, false);
}
#else
__device__ __forceinline__ float dot2(f16x2 a, f16x2 b, float c) {
    return c + (float)a[0] * (float)b[0] + (float)a[1] * (float)b[1];
}
#endif

__device__ __forceinline__ f16x2 mk2(float a, float b) {
    f16x2 r; r[0] = (f16)a; r[1] = (f16)b; return r;
}
__device__ __forceinline__ f16x2 pr(f16x8 v, int m) {
    f16x2 r; r[0] = v[2 * m]; r[1] = v[2 * m + 1]; return r;
}
__device__ __forceinline__ f16x8 pk8(float4 u, float4 v) {
    f16x8 w;
    w[0] = (f16)u.x; w[1] = (f16)u.y; w[2] = (f16)u.z; w[3] = (f16)u.w;
    w[4] = (f16)v.x; w[5] = (f16)v.y; w[6] = (f16)v.z; w[7] = (f16)v.w;
    return w;
}
__device__ __forceinline__ float sigm(float x) {
    return __builtin_amdgcn_rcpf(1.0f + __expf(-x));
}
__device__ __forceinline__ float tanh_fast(float x) {
    float e = __expf(2.0f * x);
    return 1.0f - 2.0f * __builtin_amdgcn_rcpf(e + 1.0f);
}

// Pack Whh1[:,64:128] into f16 planes wg[plane][row] so the scan kernel's
// per-step stream reads are fully coalesced (64 consecutive rows x 16 B).
__global__ void prep_pack(const float* __restrict__ Whh1, f16x8* __restrict__ wg)
{
    const int c = blockIdx.x;    // plane 0..7 -> cols 64+8c .. 71+8c
    const int t = threadIdx.x;   // gate row
    const float4* s = (const float4*)(Whh1 + t * HDIM + 64 + 8 * c);
    wg[c * GDIM + t] = pk8(s[0], s[1]);
}

// Fused 2-layer LSTM scan, one block per batch element, 512 threads.
//
// Toolchain law (rounds 0-5): VGPR budget is 128 @ 512 thr, 64 @ 1024 thr,
// immovable by launch_bounds/waves_per_eu. The fused scan needs 384 weight
// halves per thread; 128 regs can cleanly hold 96 VGPRs of weights (round-5
// precedent: 96 weight regs -> VGPR=112, zero scratch). So weights are
// deliberately tri-sourced per step, one stream per hardware pipe:
//   REGS  (96 VGPR): Whh0 row (128h) + Wih1[t,0:64] (64h)
//   LDS   (16 chunks/row, stride 17 -> conflict-free 8-way bank spread):
//          Wih1[t,64:128] (slots 0-7) + Whh1[t,0:64] (slots 8-15), 139 KB
//   L2    (shared 64 KB f16 copy in ws): Whh1[t,64:128], re-read per step,
//          double-buffered in 2-chunk batches (<=16 transient VGPRs)
// The opaque-zero asm defeats LICM so the compiler cannot hoist the
// loop-invariant weight streams back into registers (which would respill).
// Round-0's compiler-chosen alternative was 131 KB/step of scratch reloads
// through the same L2 pipe -- the dominant cost this design removes.
__global__ __launch_bounds__(512, 2)
void lstm_fused_v6(const float* __restrict__ x,
                   const float* __restrict__ Wih0,
                   const float* __restrict__ Whh0,
                   const float* __restrict__ bih0,
                   const float* __restrict__ bhh0,
                   const float* __restrict__ Wih1,
                   const float* __restrict__ Whh1,
                   const float* __restrict__ bih1,
                   const float* __restrict__ bhh1,
                   const float* __restrict__ Wfc,
                   const float* __restrict__ bfc,
                   const f16x8* __restrict__ wg,
                   float* __restrict__ out)
{
    __shared__ __align__(16) f16x8 wlds[GDIM * 17];  // 139,264 B weight rows
    __shared__ __align__(16) float xs[T_SEQ];        // 8 KB
    __shared__ __align__(16) f16   h0h[HDIM];
    __shared__ __align__(16) f16   h1h[HDIM];
    __shared__ float h0f[HDIM], h1f[HDIM];
    __shared__ float g0[GDIM], g1[GDIM];

    const int t = threadIdx.x;
    const int b = blockIdx.x;

    ((float4*)xs)[t] = ((const float4*)(x + (size_t)b * T_SEQ))[t];

    // ---- register weights: 96 VGPRs ----
    f16x2 w0[64];  // W_hh_l0[t, 0:128]
    f16x2 wi[32];  // W_ih_l1[t, 0:64]
    {
        const float4* p0 = (const float4*)(Whh0 + t * HDIM);
        const float4* p1 = (const float4*)(Wih1 + t * HDIM);
#pragma unroll
        for (int c = 0; c < 32; ++c) {
            float4 v = p0[c];
            w0[2 * c]     = mk2(v.x, v.y);
            w0[2 * c + 1] = mk2(v.z, v.w);
        }
#pragma unroll
        for (int c = 0; c < 16; ++c) {
            float4 v = p1[c];
            wi[2 * c]     = mk2(v.x, v.y);
            wi[2 * c + 1] = mk2(v.z, v.w);
        }
    }
    // ---- LDS weight row (stride 17 chunks: banks spread 8-way, no conflict) ----
    f16x8* wrow = wlds + t * 17;
    {
        const float4* p = (const float4*)(Wih1 + t * HDIM + 64);
#pragma unroll
        for (int c = 0; c < 8; ++c) wrow[c] = pk8(p[2 * c], p[2 * c + 1]);
        p = (const float4*)(Whh1 + t * HDIM);
#pragma unroll
        for (int c = 0; c < 8; ++c) wrow[8 + c] = pk8(p[2 * c], p[2 * c + 1]);
    }
    const float wx0   = Wih0[t];
    const float bias0 = bih0[t] + bhh0[t];
    const float bias1 = bih1[t] + bhh1[t];

    if (t < HDIM) {
        h0h[t] = (f16)0.f; h1h[t] = (f16)0.f;
        h0f[t] = 0.f;      h1f[t] = 0.f;
    }
    float c0r = 0.f, c1r = 0.f;
    __syncthreads();

    const f16x8* h0p = (const f16x8*)h0h;
    const f16x8* h1p = (const f16x8*)h1h;

    for (int i = 0; i <= T_SEQ; ++i) {
        int z = 0;
        asm volatile("" : "+v"(z));          // opaque zero: blocks LICM hoisting
        const f16x8* wr  = wrow + z;         // LDS weight stream
        const f16x8* wg2 = wg + z;           // L2 weight stream

        // issue stream batch 0 (planes 0,1); latency hides under phase A
        f16x8 ga = wg2[0 * GDIM + t];
        f16x8 gb = wg2[1 * GDIM + t];

        float s0a = (i < T_SEQ ? xs[i] : 0.f) * wx0 + bias0;
        float s0b = 0.f, s0c = 0.f, s0d = 0.f;
        float s1a = bias1, s1b = 0.f;

#pragma unroll
        for (int c = 0; c < 8; ++c) {        // h0 chunks 0-7: all-register
            f16x8 h = h0p[c];
            s0a = dot2(w0[4 * c + 0], pr(h, 0), s0a);
            s0b = dot2(w0[4 * c + 1], pr(h, 1), s0b);
            s0c = dot2(w0[4 * c + 2], pr(h, 2), s0c);
            s0d = dot2(w0[4 * c + 3], pr(h, 3), s0d);
            s1a = dot2(wi[4 * c + 0], pr(h, 0), s1a);
            s1b = dot2(wi[4 * c + 1], pr(h, 1), s1b);
            s1a = dot2(wi[4 * c + 2], pr(h, 2), s1a);
            s1b = dot2(wi[4 * c + 3], pr(h, 3), s1b);
        }
#pragma unroll
        for (int c = 0; c < 8; ++c) {        // h0 chunks 8-15: w0 regs + Wih1-hi LDS
            f16x8 h  = h0p[8 + c];
            f16x8 lw = wr[c];
            s0a = dot2(w0[32 + 4 * c + 0], pr(h, 0), s0a);
            s0b = dot2(w0[32 + 4 * c + 1], pr(h, 1), s0b);
            s0c = dot2(w0[32 + 4 * c + 2], pr(h, 2), s0c);
            s0d = dot2(w0[32 + 4 * c + 3], pr(h, 3), s0d);
            s1a = dot2(pr(lw, 0), pr(h, 0), s1a);
            s1b = dot2(pr(lw, 1), pr(h, 1), s1b);
            s1a = dot2(pr(lw, 2), pr(h, 2), s1a);
            s1b = dot2(pr(lw, 3), pr(h, 3), s1b);
        }
#pragma unroll
        for (int c = 0; c < 8; ++c) {        // h1 chunks 0-7: Whh1-lo LDS
            f16x8 h  = h1p[c];
            f16x8 lw = wr[8 + c];
            s1a = dot2(pr(lw, 0), pr(h, 0), s1a);
            s1b = dot2(pr(lw, 1), pr(h, 1), s1b);
            s1a = dot2(pr(lw, 2), pr(h, 2), s1a);
            s1b = dot2(pr(lw, 3), pr(h, 3), s1b);
        }
#pragma unroll
        for (int bb = 0; bb < 4; ++bb) {     // h1 chunks 8-15: L2 stream, dbuf
            f16x8 na = ga, nb = gb;
            if (bb < 3) {
                na = wg2[(2 * bb + 2) * GDIM + t];
                nb = wg2[(2 * bb + 3) * GDIM + t];
            }
            f16x8 h = h1p[8 + 2 * bb];
            s1a = dot2(pr(ga, 0), pr(h, 0), s1a);
            s1b = dot2(pr(ga, 1), pr(h, 1), s1b);
            s1a = dot2(pr(ga, 2), pr(h, 2), s1a);
            s1b = dot2(pr(ga, 3), pr(h, 3), s1b);
            h = h1p[9 + 2 * bb];
            s1a = dot2(pr(gb, 0), pr(h, 0), s1a);
            s1b = dot2(pr(gb, 1), pr(h, 1), s1b);
            s1a = dot2(pr(gb, 2), pr(h, 2), s1a);
            s1b = dot2(pr(gb, 3), pr(h, 3), s1b);
            ga = na; gb = nb;
        }
        g0[t] = (s0a + s0b) + (s0c + s0d);
        g1[t] = s1a + s1b;
        __syncthreads();

        // ---- update phase (round-0 verified logic) ----
        if (t < 128) {
            if (i < T_SEQ) {
                float gi = sigm(g0[t]);
                float gf = sigm(g0[t + 128]);
                float gg = tanh_fast(g0[t + 256]);
                float go = sigm(g0[t + 384]);
                c0r = gf * c0r + gi * gg;
                float h = go * tanh_fast(c0r);
                h0h[t] = (f16)h;
                h0f[t] = h;
            }
        } else if (t < 256) {
            if (i >= 1) {
                int j = t - 128;
                float gi = sigm(g1[j]);
                float gf = sigm(g1[j + 128]);
                float gg = tanh_fast(g1[j + 256]);
                float go = sigm(g1[j + 384]);
                c1r = gf * c1r + gi * gg;
                float h = go * tanh_fast(c1r);
                h1h[j] = (f16)h;
                h1f[j] = h;
            }
        }
        __syncthreads();
    }

    // ---- outputs: out = [ y(256) | h_n(2*256*128) | c_n(2*256*128) ] ----
    float* hn = out + BATCH;
    float* cn = out + BATCH + 2 * BATCH * HDIM;
    if (t < 128) {
        hn[(size_t)b * HDIM + t] = h0f[t];
        cn[(size_t)b * HDIM + t] = c0r;
    } else if (t < 256) {
        int j = t - 128;
        hn[BATCH * HDIM + (size_t)b * HDIM + j] = h1f[j];
        cn[BATCH * HDIM + (size_t)b * HDIM + j] = c1r;
    }
    if (t < 64) {
        float p = h1f[t] * Wfc[t] + h1f[t + 64] * Wfc[t + 64];
#pragma unroll
        for (int o = 32; o >= 1; o >>= 1) p += __shfl_down(p, o);
        if (t == 0) out[b] = p + bfc[0];
    }
}

// ======== fallback (workspace too small) — round-2 kernel, verified ========
__global__ __launch_bounds__(1024)
void lstm_fused_fb(const float* __restrict__ x,
                   const float* __restrict__ Wih0,
                   const float* __restrict__ Whh0,
                   const float* __restrict__ bih0,
                   const float* __restrict__ bhh0,
                   const float* __restrict__ Wih1,
                   const float* __restrict__ Whh1,
                   const float* __restrict__ bih1,
                   const float* __restrict__ bhh1,
                   const float* __restrict__ Wfc,
                   const float* __restrict__ bfc,
                   float* __restrict__ out)
{
    __shared__ __align__(16) float xs[T_SEQ];
    __shared__ __align__(16) f16   h0h[HDIM];
    __shared__ __align__(16) f16   h1h[HDIM];
    __shared__ float h0f[HDIM], h1f[HDIM];
    __shared__ float g0[GDIM];
    __shared__ float g1a[GDIM], g1b[GDIM];

    const int t  = threadIdx.x;
    const int b  = blockIdx.x;
    const bool gA = (t < 512);
    const int r  = t & 511;

    if (gA)
        ((float4*)xs)[t] = ((const float4*)(x + (size_t)b * T_SEQ))[t];

    f16x2 wa[64];
    f16x2 wb[32];
    {
        const float4* pa = (const float4*)((gA ? Whh0 : Wih1) + r * HDIM);
        const float4* pb = (const float4*)(Whh1 + r * HDIM + (gA ? 0 : 64));
#pragma unroll
        for (int c = 0; c < 32; ++c) {
            float4 v = pa[c];
            wa[2 * c]     = mk2(v.x, v.y);
            wa[2 * c + 1] = mk2(v.z, v.w);
        }
#pragma unroll
        for (int c = 0; c < 16; ++c) {
            float4 v = pb[c];
            wb[2 * c]     = mk2(v.x, v.y);
            wb[2 * c + 1] = mk2(v.z, v.w);
        }
    }
    const float xw   = gA ? Wih0[r] : 0.f;
    const float bias = gA ? (bih0[r] + bhh0[r]) : (bih1[r] + bhh1[r]);

    if (t < HDIM) {
        h0h[t] = (f16)0.f; h1h[t] = (f16)0.f;
        h0f[t] = 0.f;      h1f[t] = 0.f;
    }
    float c0r = 0.f, c1r = 0.f;
    __syncthreads();

    const f16x8* h0p  = (const f16x8*)h0h;
    const f16x8* hsel = ((const f16x8*)h1h) + (gA ? 0 : 8);

    for (int i = 0; i <= T_SEQ; ++i) {
        float sa = (i < T_SEQ ? xs[i] : 0.f) * xw + bias;
        float sb = 0.f, sc = 0.f, sd = 0.f;
#pragma unroll
        for (int c = 0; c < 16; ++c) {
            f16x8 h = h0p[c];
            sa = dot2(wa[4 * c + 0], pr(h, 0), sa);
            sb = dot2(wa[4 * c + 1], pr(h, 1), sb);
            sa = dot2(wa[4 * c + 2], pr(h, 2), sa);
            sb = dot2(wa[4 * c + 3], pr(h, 3), sb);
        }
#pragma unroll
        for (int c = 0; c < 8; ++c) {
            f16x8 h = hsel[c];
            sc = dot2(wb[4 * c + 0], pr(h, 0), sc);
            sd = dot2(wb[4 * c + 1], pr(h, 1), sd);
            sc = dot2(wb[4 * c + 2], pr(h, 2), sc);
            sd = dot2(wb[4 * c + 3], pr(h, 3), sd);
        }
        if (gA) { g0[r] = sa + sb; g1a[r] = sc + sd; }
        else    { g1b[r] = (sa + sb) + (sc + sd); }
        __syncthreads();

        if (t < 128) {
            if (i < T_SEQ) {
                float gi = sigm(g0[t]);
                float gf = sigm(g0[t + 128]);
                float gg = tanh_fast(g0[t + 256]);
                float go = sigm(g0[t + 384]);
                c0r = gf * c0r + gi * gg;
                float h = go * tanh_fast(c0r);
                h0h[t] = (f16)h;
                h0f[t] = h;
            }
        } else if (t >= 512 && t < 640) {
            if (i >= 1) {
                int j = t - 512;
                float gi = sigm(g1a[j]       + g1b[j]);
                float gf = sigm(g1a[j + 128] + g1b[j + 128]);
                float gg = tanh_fast(g1a[j + 256] + g1b[j + 256]);
                float go = sigm(g1a[j + 384] + g1b[j + 384]);
                c1r = gf * c1r + gi * gg;
                float h = go * tanh_fast(c1r);
                h1h[j] = (f16)h;
                h1f[j] = h;
            }
        }
        __syncthreads();
    }

    float* hn = out + BATCH;
    float* cn = out + BATCH + 2 * BATCH * HDIM;
    if (t < 128) {
        hn[(size_t)b * HDIM + t] = h0f[t];
        cn[(size_t)b * HDIM + t] = c0r;
    } else if (t >= 512 && t < 640) {
        int j = t - 512;
        hn[BATCH * HDIM + (size_t)b * HDIM + j] = h1f[j];
        cn[BATCH * HDIM + (size_t)b * HDIM + j] = c1r;
    }
    if (t < 64) {
        float p = h1f[t] * Wfc[t] + h1f[t + 64] * Wfc[t + 64];
#pragma unroll
        for (int o = 32; o >= 1; o >>= 1) p += __shfl_down(p, o);
        if (t == 0) out[b] = p + bfc[0];
    }
}

extern "C" void kernel_launch(void* const* d_in, const int* in_sizes, int n_in,
                              void* d_out, int out_size, void* d_ws, size_t ws_size,
                              hipStream_t stream) {
    const float* x    = (const float*)d_in[0];
    const float* Wih0 = (const float*)d_in[1];
    const float* Whh0 = (const float*)d_in[2];
    const float* bih0 = (const float*)d_in[3];
    const float* bhh0 = (const float*)d_in[4];
    const float* Wih1 = (const float*)d_in[5];
    const float* Whh1 = (const float*)d_in[6];
    const float* bih1 = (const float*)d_in[7];
    const float* bhh1 = (const float*)d_in[8];
    const float* Wfc  = (const float*)d_in[9];
    const float* bfc  = (const float*)d_in[10];
    float* out = (float*)d_out;

    if (d_ws && ws_size >= (size_t)WS_NEED) {
        f16x8* wg = (f16x8*)d_ws;
        prep_pack<<<GW_PLANES, GDIM, 0, stream>>>(Whh1, wg);
        lstm_fused_v6<<<BATCH, GDIM, 0, stream>>>(x, Wih0, Whh0, bih0, bhh0,
                                                  Wih1, Whh1, bih1, bhh1,
                                                  Wfc, bfc, wg, out);
    } else {
        lstm_fused_fb<<<BATCH, 1024, 0, stream>>>(x, Wih0, Whh0, bih0, bhh0,
                                                  Wih1, Whh1, bih1, bhh1,
                                                  Wfc, bfc, out);
    }
}